// Round 11
// baseline (246.308 us; speedup 1.0000x reference)
//
#include <hip/hip_runtime.h>
#include <math.h>

#define KNN_EPS 1e-8f
// Spatial grid: domain [0,256)^3, cell h=16 -> 16^3 = 4096 cells, ~4.9 refs/cell.
#define GH 16.0f
#define GC 16
#define NCELLS (GC * GC * GC)
#define MARGIN 1.0f   // >> max |noisy_d - true_d| (~0.05) -> safe pruning

// ---------------------------------------------------------------------------
// Validated arithmetic (round 8, absmax 0.0547):
//   rsq/qsq: non-fused sequential squares; t: asc FMA chain;
//   d = max(fma(-2,t,fl(qsq+rsq)), 0); epilogue: +eps, IEEE div, seq sums.
// Selection: (d, idx) lexicographic min-3 == ascending-index strict-< scan.
// DO NOT change roundings -- only execution structure.
// ---------------------------------------------------------------------------

__device__ __forceinline__ int cell_coord(float v) {
    int c = (int)floorf(v * (1.0f / GH));
    return min(max(c, 0), GC - 1);
}

__global__ void count_kernel(const float* __restrict__ xyz1,
                             int* __restrict__ counts, int n1) {
    int i = blockIdx.x * blockDim.x + threadIdx.x;
    if (i < n1) {
        float x = xyz1[3 * i + 0];
        float y = xyz1[3 * i + 1];
        float z = xyz1[3 * i + 2];
        int cid = (cell_coord(z) * GC + cell_coord(y)) * GC + cell_coord(x);
        atomicAdd(&counts[cid], 1);
    }
}

// exclusive scan of 4096 counts -> starts[0..4096], cursor copy. 1 block.
__global__ __launch_bounds__(256) void scan_kernel(
    const int* __restrict__ counts,
    int* __restrict__ starts,
    int* __restrict__ cursor) {
    __shared__ int lds[256];
    const int t = threadIdx.x;
    const int base = t * 16;
    int local[16];
    int s = 0;
    for (int k = 0; k < 16; ++k) { local[k] = counts[base + k]; s += local[k]; }
    lds[t] = s;
    __syncthreads();
    for (int off = 1; off < 256; off <<= 1) {
        int v = (t >= off) ? lds[t - off] : 0;
        __syncthreads();
        lds[t] += v;
        __syncthreads();
    }
    int run = lds[t] - s;   // exclusive
    for (int k = 0; k < 16; ++k) {
        starts[base + k] = run;
        cursor[base + k] = run;
        run += local[k];
    }
    if (t == 255) starts[NCELLS] = run;
}

// sorted4 packs (x, y, z, bitcast(original index)) -> ONE dwordx4 gather per
// candidate; rsq is recomputed in-query with the validated rounding (bit-equal).
__global__ void scatter_kernel(const float* __restrict__ xyz1,
                               int* __restrict__ cursor,
                               float4* __restrict__ sorted4, int n1) {
    int i = blockIdx.x * blockDim.x + threadIdx.x;
    if (i < n1) {
        float x = xyz1[3 * i + 0];
        float y = xyz1[3 * i + 1];
        float z = xyz1[3 * i + 2];
        int cid = (cell_coord(z) * GC + cell_coord(y)) * GC + cell_coord(x);
        int pos = atomicAdd(&cursor[cid], 1);
        sorted4[pos] = make_float4(x, y, z, __int_as_float(i));
    }
}

// (d, idx)-lexicographic insert: order-independent, identical result to the
// validated ascending-index strict-< scan (stable top_k ties).
__device__ __forceinline__ void top3_insert_lex(float d, int j,
                                                float& bd0, float& bd1, float& bd2,
                                                int& bi0, int& bi1, int& bi2) {
    if (d < bd2 || (d == bd2 && j < bi2)) {
        if (d < bd1 || (d == bd1 && j < bi1)) {
            bd2 = bd1; bi2 = bi1;
            if (d < bd0 || (d == bd0 && j < bi0)) {
                bd1 = bd0; bi1 = bi0;
                bd0 = d;   bi0 = j;
            } else {
                bd1 = d;   bi1 = j;
            }
        } else {
            bd2 = d;       bi2 = j;
        }
    }
}

// Validated candidate evaluation (round 8 roundings, rsq recomputed bit-equal)
__device__ __forceinline__ void eval_candidate(
    float4 r, float qx, float qy, float qz, float qsq,
    float& bd0, float& bd1, float& bd2, int& bi0, int& bi1, int& bi2) {
    int ridx = __float_as_int(r.w);
    float rsq = r.x * r.x + r.y * r.y;
    rsq = rsq + r.z * r.z;
    float t = fmaf(qz, r.z, fmaf(qy, r.y, qx * r.x));
    float h = qsq + rsq;
    float d = fmaxf(fmaf(-2.0f, t, h), 0.0f);
    top3_insert_lex(d, ridx, bd0, bd1, bd2, bi0, bi1, bi2);
}

// Pass 1: grid (ceil(nq/256), 3). Chunk ch scans the z-plane icz+(ch-1) of the
// 3x3x3 neighborhood; the 3 x-adjacent cells per row are CONTIGUOUS in the
// sorted array -> one range per row, 3 row-ranges preloaded up front (MLP).
__global__ __launch_bounds__(256) void knn_partial_kernel(
    const float4* __restrict__ sorted4,
    const int*   __restrict__ starts,
    const float* __restrict__ xyz2,
    const float* __restrict__ motion,
    float* __restrict__ pd,   // [3 * nq * 3]
    int*   __restrict__ pi,   // [3 * nq * 3]
    int n2, int C)
{
#pragma clang fp contract(off)
    const int qid = blockIdx.x * blockDim.x + threadIdx.x;
    const int nq = n2 * C;
    if (qid >= nq) return;

    const int chunk = blockIdx.y;          // 0,1,2 -> dz = -1,0,+1
    const long base = ((long)chunk * nq + qid) * 3;

    const int n = qid / C;

    const float qx = xyz2[3 * n + 0] + motion[3 * qid + 0];
    const float qy = xyz2[3 * n + 1] + motion[3 * qid + 1];
    const float qz = xyz2[3 * n + 2] + motion[3 * qid + 2];

    float qsq = qx * qx + qy * qy;
    qsq = qsq + qz * qz;

    float bd0 = INFINITY, bd1 = INFINITY, bd2 = INFINITY;
    int   bi0 = 0,        bi1 = 0,        bi2 = 0;

    const int cz = cell_coord(qz) + (chunk - 1);
    if (cz >= 0 && cz < GC) {
        const int icx = cell_coord(qx);
        const int icy = cell_coord(qy);
        const int x0 = max(icx - 1, 0);
        const int x1 = min(icx + 1, GC - 1);
        const int xw = x1 - x0 + 1;

        // preload all row ranges first (independent loads -> MLP)
        int rs[3], re[3];
        int nrows = 0;
        for (int dy = -1; dy <= 1; ++dy) {
            int cy = icy + dy;
            if (cy < 0 || cy >= GC) continue;
            int rowbase = (cz * GC + cy) * GC + x0;
            rs[nrows] = starts[rowbase];
            re[nrows] = starts[rowbase + xw];
            ++nrows;
        }
        for (int rr = 0; rr < nrows; ++rr) {
            for (int s = rs[rr]; s < re[rr]; ++s) {
                eval_candidate(sorted4[s], qx, qy, qz, qsq,
                               bd0, bd1, bd2, bi0, bi1, bi2);
            }
        }
    }

    pd[base + 0] = bd0;  pd[base + 1] = bd1;  pd[base + 2] = bd2;
    pi[base + 0] = bi0;  pi[base + 1] = bi1;  pi[base + 2] = bi2;
}

// Pass 2: merge 3 plane-local top-3 lists (order-independent lex insert),
// escalate to shells rho>=2 ONLY if the ring-1 bound can't certify top-3
// (face-adjacent queries; ~1e-5 of queries), then validated epilogue.
__global__ __launch_bounds__(256) void knn_merge_kernel(
    const float* __restrict__ pd,
    const int*   __restrict__ pi,
    const float4* __restrict__ sorted4,
    const int*   __restrict__ starts,
    const float* __restrict__ xyz2,
    const float* __restrict__ motion,
    const float* __restrict__ point1,
    float* __restrict__ out,
    int n2, int C)
{
#pragma clang fp contract(off)
    const int qid = blockIdx.x * blockDim.x + threadIdx.x;
    const int nq = n2 * C;
    if (qid >= nq) return;

    const int n = qid / C;
    const int c = qid - n * C;

    float bd0 = INFINITY, bd1 = INFINITY, bd2 = INFINITY;
    int   bi0 = 0,        bi1 = 0,        bi2 = 0;

    for (int ch = 0; ch < 3; ++ch) {
        const long base = ((long)ch * nq + qid) * 3;
        for (int k = 0; k < 3; ++k) {
            float d = pd[base + k];
            int   i = pi[base + k];
            if (d < INFINITY)
                top3_insert_lex(d, i, bd0, bd1, bd2, bi0, bi1, bi2);
        }
    }

    // ring-1 certification: unscanned cells have true d^2 >= (1*GH)^2 = 256
    if (!(bd2 + MARGIN <= 256.0f)) {
        // rare escalation path (recompute query, scan shells rho>=2)
        const float qx = xyz2[3 * n + 0] + motion[3 * qid + 0];
        const float qy = xyz2[3 * n + 1] + motion[3 * qid + 1];
        const float qz = xyz2[3 * n + 2] + motion[3 * qid + 2];
        float qsq = qx * qx + qy * qy;
        qsq = qsq + qz * qz;
        const int icx = cell_coord(qx);
        const int icy = cell_coord(qy);
        const int icz = cell_coord(qz);

        for (int rho = 2; rho < GC; ++rho) {
            for (int dz = -rho; dz <= rho; ++dz) {
                int cz = icz + dz;
                if (cz < 0 || cz >= GC) continue;
                int adz = (dz < 0) ? -dz : dz;
                for (int dy = -rho; dy <= rho; ++dy) {
                    int cy = icy + dy;
                    if (cy < 0 || cy >= GC) continue;
                    int ady = (dy < 0) ? -dy : dy;
                    int step = (adz == rho || ady == rho) ? 1 : 2 * rho;
                    for (int dx = -rho; dx <= rho; dx += step) {
                        int cx = icx + dx;
                        if (cx < 0 || cx >= GC) continue;
                        int cid = (cz * GC + cy) * GC + cx;
                        int s = starts[cid];
                        int e = starts[cid + 1];
                        for (; s < e; ++s) {
                            eval_candidate(sorted4[s], qx, qy, qz, qsq,
                                           bd0, bd1, bd2, bi0, bi1, bi2);
                        }
                    }
                }
            }
            float rd = (float)rho * GH;
            if (bd2 + MARGIN <= rd * rd) break;
        }
    }

    // epilogue, numpy fp32 order (validated round 8)
    float dd0 = bd0 + KNN_EPS;
    float dd1 = bd1 + KNN_EPS;
    float dd2 = bd2 + KNN_EPS;

    float w0 = 1.0f / dd0;
    float w1 = 1.0f / dd1;
    float w2 = 1.0f / dd2;
    float s  = w0 + w1;
    s = s + w2;
    float m = fmaxf(s, 3.0f);
    w0 = w0 / m;
    w1 = w1 / m;
    w2 = w2 / m;

    float p0 = point1[bi0 * C + c];
    float p1 = point1[bi1 * C + c];
    float p2 = point1[bi2 * C + c];

    float acc = w0 * p0 + w1 * p1;
    acc = acc + w2 * p2;
    out[qid] = acc;
}

extern "C" void kernel_launch(void* const* d_in, const int* in_sizes, int n_in,
                              void* d_out, int out_size, void* d_ws, size_t ws_size,
                              hipStream_t stream) {
    const float* xyz1   = (const float*)d_in[0];
    const float* point1 = (const float*)d_in[1];
    const float* xyz2   = (const float*)d_in[2];
    const float* motion = (const float*)d_in[3];
    float* out = (float*)d_out;

    const int n1 = in_sizes[0] / 3;
    const int n2 = in_sizes[2] / 3;
    const int C  = in_sizes[1] / n1;
    const int nq = n2 * C;

    // ws layout: sorted4 | counts | starts | cursor | pd | pi
    char* ws = (char*)d_ws;
    size_t off = 0;
    auto alloc = [&](size_t bytes) {
        char* p = ws + off;
        off = (off + bytes + 255) & ~(size_t)255;
        return p;
    };
    float4* sorted4 = (float4*)alloc((size_t)n1 * 16);
    int*    counts  = (int*)alloc((size_t)NCELLS * 4);
    int*    starts  = (int*)alloc((size_t)(NCELLS + 1) * 4);
    int*    cursor  = (int*)alloc((size_t)NCELLS * 4);
    float*  pd      = (float*)alloc((size_t)3 * nq * 3 * 4);
    int*    pi      = (int*)alloc((size_t)3 * nq * 3 * 4);

    hipMemsetAsync(counts, 0, (size_t)NCELLS * 4, stream);
    count_kernel<<<(n1 + 255) / 256, 256, 0, stream>>>(xyz1, counts, n1);
    scan_kernel<<<1, 256, 0, stream>>>(counts, starts, cursor);
    scatter_kernel<<<(n1 + 255) / 256, 256, 0, stream>>>(xyz1, cursor, sorted4, n1);

    dim3 grid((nq + 255) / 256, 3);
    knn_partial_kernel<<<grid, 256, 0, stream>>>(
        sorted4, starts, xyz2, motion, pd, pi, n2, C);

    knn_merge_kernel<<<(nq + 255) / 256, 256, 0, stream>>>(
        pd, pi, sorted4, starts, xyz2, motion, point1, out, n2, C);
}

// Round 12
// 218.063 us; speedup vs baseline: 1.1295x; 1.1295x over previous
//
#include <hip/hip_runtime.h>
#include <math.h>

#define KNN_EPS 1e-8f
// Spatial grid: domain [0,256)^3, cell h=16 -> 16^3 = 4096 cells, ~4.9 refs/cell.
#define GH 16.0f
#define GC 16
#define NCELLS (GC * GC * GC)
#define MARGIN 1.0f   // >> max |noisy_d - true_d| (~0.05) -> safe pruning
#define CAP 512       // staged candidates per block (8 KB LDS); 27-cell mean=132,
                      // P(>512) ~ e^-180; overflow path keeps correctness anyway

// ---------------------------------------------------------------------------
// Validated arithmetic (round 8, absmax 0.0547):
//   rsq/qsq: non-fused sequential squares; t: asc FMA chain;
//   d = max(fma(-2,t,fl(qsq+rsq)), 0); epilogue: +eps, IEEE div, seq sums.
// Selection: (d, idx) lexicographic min-3 == ascending-index strict-< scan,
// independent of scan order (validated: absmax bit-identical across r10/r11).
// DO NOT change roundings -- only execution structure.
// ---------------------------------------------------------------------------

__device__ __forceinline__ int cell_coord(float v) {
    int c = (int)floorf(v * (1.0f / GH));
    return min(max(c, 0), GC - 1);
}

__global__ void count_refs_kernel(const float* __restrict__ xyz1,
                                  int* __restrict__ counts, int n1) {
    int i = blockIdx.x * blockDim.x + threadIdx.x;
    if (i < n1) {
        int cid = (cell_coord(xyz1[3 * i + 2]) * GC +
                   cell_coord(xyz1[3 * i + 1])) * GC +
                   cell_coord(xyz1[3 * i + 0]);
        atomicAdd(&counts[cid], 1);
    }
}

// Pack each query as (qx,qy,qz,bitcast(qid)) with the validated fp32 add,
// and count queries per cell.
__global__ void pack_queries_kernel(const float* __restrict__ xyz2,
                                    const float* __restrict__ motion,
                                    float4* __restrict__ q4,
                                    int* __restrict__ qcounts,
                                    int n2, int C) {
#pragma clang fp contract(off)
    int qid = blockIdx.x * blockDim.x + threadIdx.x;
    int nq = n2 * C;
    if (qid < nq) {
        int n = qid / C;
        float qx = xyz2[3 * n + 0] + motion[3 * qid + 0];
        float qy = xyz2[3 * n + 1] + motion[3 * qid + 1];
        float qz = xyz2[3 * n + 2] + motion[3 * qid + 2];
        q4[qid] = make_float4(qx, qy, qz, __int_as_float(qid));
        int cid = (cell_coord(qz) * GC + cell_coord(qy)) * GC + cell_coord(qx);
        atomicAdd(&qcounts[cid], 1);
    }
}

__device__ void scan4096(const int* __restrict__ cnt, int* __restrict__ st,
                         int* __restrict__ cur, int* lds) {
    const int t = threadIdx.x;
    const int base = t * 16;
    int local[16];
    int s = 0;
    for (int k = 0; k < 16; ++k) { local[k] = cnt[base + k]; s += local[k]; }
    lds[t] = s;
    __syncthreads();
    for (int off = 1; off < 256; off <<= 1) {
        int v = (t >= off) ? lds[t - off] : 0;
        __syncthreads();
        lds[t] += v;
        __syncthreads();
    }
    int run = lds[t] - s;   // exclusive
    for (int k = 0; k < 16; ++k) {
        st[base + k] = run;
        cur[base + k] = run;
        run += local[k];
    }
    if (t == 255) st[NCELLS] = run;
}

__global__ __launch_bounds__(256) void scan2_kernel(
    const int* __restrict__ counts,  int* __restrict__ starts,  int* __restrict__ cursor,
    const int* __restrict__ qcounts, int* __restrict__ qstarts, int* __restrict__ qcursor) {
    __shared__ int lds[256];
    scan4096(counts, starts, cursor, lds);
    __syncthreads();
    scan4096(qcounts, qstarts, qcursor, lds);
}

__global__ void scatter_refs_kernel(const float* __restrict__ xyz1,
                                    int* __restrict__ cursor,
                                    float4* __restrict__ sorted4, int n1) {
    int i = blockIdx.x * blockDim.x + threadIdx.x;
    if (i < n1) {
        float x = xyz1[3 * i + 0];
        float y = xyz1[3 * i + 1];
        float z = xyz1[3 * i + 2];
        int cid = (cell_coord(z) * GC + cell_coord(y)) * GC + cell_coord(x);
        int pos = atomicAdd(&cursor[cid], 1);
        sorted4[pos] = make_float4(x, y, z, __int_as_float(i));
    }
}

__global__ void scatter_queries_kernel(const float4* __restrict__ q4,
                                       int* __restrict__ qcursor,
                                       float4* __restrict__ qsorted4, int nq) {
    int i = blockIdx.x * blockDim.x + threadIdx.x;
    if (i < nq) {
        float4 Q = q4[i];
        int cid = (cell_coord(Q.z) * GC + cell_coord(Q.y)) * GC + cell_coord(Q.x);
        int pos = atomicAdd(&qcursor[cid], 1);
        qsorted4[pos] = Q;
    }
}

// (d, idx)-lexicographic insert: order-independent == validated stable scan.
__device__ __forceinline__ void top3_insert_lex(float d, int j,
                                                float& bd0, float& bd1, float& bd2,
                                                int& bi0, int& bi1, int& bi2) {
    if (d < bd2 || (d == bd2 && j < bi2)) {
        if (d < bd1 || (d == bd1 && j < bi1)) {
            bd2 = bd1; bi2 = bi1;
            if (d < bd0 || (d == bd0 && j < bi0)) {
                bd1 = bd0; bi1 = bi0;
                bd0 = d;   bi0 = j;
            } else {
                bd1 = d;   bi1 = j;
            }
        } else {
            bd2 = d;       bi2 = j;
        }
    }
}

// Validated candidate evaluation (round 8 roundings, rsq recomputed bit-equal)
__device__ __forceinline__ void eval_candidate(
    float4 r, float qx, float qy, float qz, float qsq,
    float& bd0, float& bd1, float& bd2, int& bi0, int& bi1, int& bi2) {
    int ridx = __float_as_int(r.w);
    float rsq = r.x * r.x + r.y * r.y;
    rsq = rsq + r.z * r.z;
    float t = fmaf(qz, r.z, fmaf(qy, r.y, qx * r.x));
    float h = qsq + rsq;
    float d = fmaxf(fmaf(-2.0f, t, h), 0.0f);
    top3_insert_lex(d, ridx, bd0, bd1, bd2, bi0, bi1, bi2);
}

// Rigorous certification radius after scanning cell-rings <= rho around
// (icx,icy,icz): min distance from q to any region NOT yet scanned.
// INF if the whole grid is covered.
__device__ __forceinline__ float cert_radius(float qx, float qy, float qz,
                                             int icx, int icy, int icz, int rho) {
    float R = INFINITY;
    if (icx - rho > 0)      R = fminf(R, qx - (float)(icx - rho) * GH);
    if (icx + rho < GC - 1) R = fminf(R, (float)(icx + rho + 1) * GH - qx);
    if (icy - rho > 0)      R = fminf(R, qy - (float)(icy - rho) * GH);
    if (icy + rho < GC - 1) R = fminf(R, (float)(icy + rho + 1) * GH - qy);
    if (icz - rho > 0)      R = fminf(R, qz - (float)(icz - rho) * GH);
    if (icz + rho < GC - 1) R = fminf(R, (float)(icz + rho + 1) * GH - qz);
    return R;
}

// One block per cell: stage the 27-cell candidate list into LDS once
// (coalesced), then every lane evaluates from LDS broadcasts -- uniform
// trip counts (no divergence), no per-candidate gathers.
__global__ __launch_bounds__(64) void knn_cell_kernel(
    const float4* __restrict__ sorted4,
    const int*   __restrict__ starts,
    const float4* __restrict__ qsorted4,
    const int*   __restrict__ qstarts,
    const float* __restrict__ point1,
    float* __restrict__ out,
    int C)
{
#pragma clang fp contract(off)
    const int cell = blockIdx.x;
    const int qs = qstarts[cell];
    const int qe = qstarts[cell + 1];
    if (qs == qe) return;

    const int icx = cell & (GC - 1);
    const int icy = (cell >> 4) & (GC - 1);
    const int icz = cell >> 8;

    __shared__ float4 cand[CAP];
    __shared__ int rowg0[9], rowlen[9], rowsta[9], rowlds[9];
    __shared__ int nrows_s, total_s, ovf_s;

    if (threadIdx.x == 0) {
        const int x0 = max(icx - 1, 0);
        const int xw = min(icx + 1, GC - 1) - x0 + 1;
        int nr = 0, lds = 0, ovf = 0;
        for (int dz = -1; dz <= 1; ++dz) {
            int cz = icz + dz;
            if (cz < 0 || cz >= GC) continue;
            for (int dy = -1; dy <= 1; ++dy) {
                int cy = icy + dy;
                if (cy < 0 || cy >= GC) continue;
                int rb = (cz * GC + cy) * GC + x0;
                int g0 = starts[rb];
                int len = starts[rb + xw] - g0;
                int st = min(len, CAP - lds);
                if (st < 0) st = 0;
                rowg0[nr] = g0; rowlen[nr] = len;
                rowsta[nr] = st; rowlds[nr] = lds;
                lds += st;
                if (st < len) ovf = 1;
                ++nr;
            }
        }
        nrows_s = nr; total_s = lds; ovf_s = ovf;
    }
    __syncthreads();

    const int nrows = nrows_s;
    for (int r = 0; r < nrows; ++r) {
        const int st = rowsta[r], g0 = rowg0[r], lb = rowlds[r];
        for (int k = threadIdx.x; k < st; k += 64)
            cand[lb + k] = sorted4[g0 + k];
    }
    __syncthreads();

    const int total = total_s;
    const int ovf = ovf_s;

    for (int q = qs + threadIdx.x; q < qe; q += 64) {
        float4 Q = qsorted4[q];
        const float qx = Q.x, qy = Q.y, qz = Q.z;
        const int qid = __float_as_int(Q.w);
        float qsq = qx * qx + qy * qy;
        qsq = qsq + qz * qz;

        float bd0 = INFINITY, bd1 = INFINITY, bd2 = INFINITY;
        int   bi0 = 0,        bi1 = 0,        bi2 = 0;

        for (int k = 0; k < total; ++k)
            eval_candidate(cand[k], qx, qy, qz, qsq, bd0, bd1, bd2, bi0, bi1, bi2);

        if (ovf) {  // LDS overflow remainder (practically never taken)
            for (int r = 0; r < nrows; ++r)
                for (int k = rowsta[r]; k < rowlen[r]; ++k)
                    eval_candidate(sorted4[rowg0[r] + k], qx, qy, qz, qsq,
                                   bd0, bd1, bd2, bi0, bi1, bi2);
        }

        // rigorous ring-1 certification; rare escalation to rings >= 2
        float R = cert_radius(qx, qy, qz, icx, icy, icz, 1);
        if (!(bd2 + MARGIN <= R * R)) {
            for (int rho = 2; rho < GC; ++rho) {
                for (int dz = -rho; dz <= rho; ++dz) {
                    int cz = icz + dz;
                    if (cz < 0 || cz >= GC) continue;
                    int adz = (dz < 0) ? -dz : dz;
                    for (int dy = -rho; dy <= rho; ++dy) {
                        int cy = icy + dy;
                        if (cy < 0 || cy >= GC) continue;
                        int ady = (dy < 0) ? -dy : dy;
                        int step = (adz == rho || ady == rho) ? 1 : 2 * rho;
                        for (int dx = -rho; dx <= rho; dx += step) {
                            int cx = icx + dx;
                            if (cx < 0 || cx >= GC) continue;
                            int cid = (cz * GC + cy) * GC + cx;
                            int s = starts[cid];
                            int e = starts[cid + 1];
                            for (; s < e; ++s)
                                eval_candidate(sorted4[s], qx, qy, qz, qsq,
                                               bd0, bd1, bd2, bi0, bi1, bi2);
                        }
                    }
                }
                float Rr = cert_radius(qx, qy, qz, icx, icy, icz, rho);
                if (bd2 + MARGIN <= Rr * Rr) break;  // Rr=INF also breaks
            }
        }

        // epilogue, numpy fp32 order (validated round 8)
        float dd0 = bd0 + KNN_EPS;
        float dd1 = bd1 + KNN_EPS;
        float dd2 = bd2 + KNN_EPS;

        float w0 = 1.0f / dd0;
        float w1 = 1.0f / dd1;
        float w2 = 1.0f / dd2;
        float s  = w0 + w1;
        s = s + w2;
        float m = fmaxf(s, 3.0f);
        w0 = w0 / m;
        w1 = w1 / m;
        w2 = w2 / m;

        const int c = qid - (qid / C) * C;
        float p0 = point1[bi0 * C + c];
        float p1 = point1[bi1 * C + c];
        float p2 = point1[bi2 * C + c];

        float acc = w0 * p0 + w1 * p1;
        acc = acc + w2 * p2;
        out[qid] = acc;
    }
}

extern "C" void kernel_launch(void* const* d_in, const int* in_sizes, int n_in,
                              void* d_out, int out_size, void* d_ws, size_t ws_size,
                              hipStream_t stream) {
    const float* xyz1   = (const float*)d_in[0];
    const float* point1 = (const float*)d_in[1];
    const float* xyz2   = (const float*)d_in[2];
    const float* motion = (const float*)d_in[3];
    float* out = (float*)d_out;

    const int n1 = in_sizes[0] / 3;
    const int n2 = in_sizes[2] / 3;
    const int C  = in_sizes[1] / n1;
    const int nq = n2 * C;

    // ws layout (~5.6 MB total)
    char* ws = (char*)d_ws;
    size_t off = 0;
    auto alloc = [&](size_t bytes) {
        char* p = ws + off;
        off = (off + bytes + 255) & ~(size_t)255;
        return p;
    };
    float4* sorted4  = (float4*)alloc((size_t)n1 * 16);
    float4* q4       = (float4*)alloc((size_t)nq * 16);
    float4* qsorted4 = (float4*)alloc((size_t)nq * 16);
    int* countsBoth  = (int*)alloc((size_t)2 * NCELLS * 4);  // counts | qcounts
    int* starts      = (int*)alloc((size_t)(NCELLS + 1) * 4);
    int* qstarts     = (int*)alloc((size_t)(NCELLS + 1) * 4);
    int* cursor      = (int*)alloc((size_t)NCELLS * 4);
    int* qcursor     = (int*)alloc((size_t)NCELLS * 4);
    int* counts  = countsBoth;
    int* qcounts = countsBoth + NCELLS;

    hipMemsetAsync(countsBoth, 0, (size_t)2 * NCELLS * 4, stream);
    count_refs_kernel<<<(n1 + 255) / 256, 256, 0, stream>>>(xyz1, counts, n1);
    pack_queries_kernel<<<(nq + 255) / 256, 256, 0, stream>>>(
        xyz2, motion, q4, qcounts, n2, C);
    scan2_kernel<<<1, 256, 0, stream>>>(counts, starts, cursor,
                                        qcounts, qstarts, qcursor);
    scatter_refs_kernel<<<(n1 + 255) / 256, 256, 0, stream>>>(
        xyz1, cursor, sorted4, n1);
    scatter_queries_kernel<<<(nq + 255) / 256, 256, 0, stream>>>(
        q4, qcursor, qsorted4, nq);
    knn_cell_kernel<<<NCELLS, 64, 0, stream>>>(
        sorted4, starts, qsorted4, qstarts, point1, out, C);
}

// Round 13
// 184.940 us; speedup vs baseline: 1.3318x; 1.1791x over previous
//
#include <hip/hip_runtime.h>
#include <math.h>

#define KNN_EPS 1e-8f
// Spatial grid: domain [0,256)^3, cell h=16 -> 16^3 = 4096 cells, ~4.9 refs/cell.
#define GH 16.0f
#define GC 16
#define NCELLS (GC * GC * GC)
#define MARGIN 1.0f   // >> max |noisy_d - true_d| (~0.05) -> safe pruning
#define CAP 384       // staged candidates per block (6 KB); 27-cell mean=132,
                      // P(>384) ~ e^-200; overflow path keeps correctness anyway

// ---------------------------------------------------------------------------
// Validated arithmetic (round 8, absmax 0.0547):
//   rsq/qsq: non-fused sequential squares; t: asc FMA chain;
//   d = max(fma(-2,t,fl(qsq+rsq)), 0); epilogue: +eps, IEEE div, seq sums.
// Selection: (d, idx) lexicographic min-3 -- order-independent, bit-identical
// across r10/r11/r12 restructures. DO NOT change roundings.
// ---------------------------------------------------------------------------

__device__ __forceinline__ int cell_coord(float v) {
    int c = (int)floorf(v * (1.0f / GH));
    return min(max(c, 0), GC - 1);
}

// Fused: ref counting + query pack/count in one launch.
__global__ void fused_count_kernel(const float* __restrict__ xyz1, int n1,
                                   const float* __restrict__ xyz2,
                                   const float* __restrict__ motion,
                                   float4* __restrict__ q4,
                                   int* __restrict__ counts,
                                   int* __restrict__ qcounts,
                                   int n2, int C) {
#pragma clang fp contract(off)
    int i = blockIdx.x * blockDim.x + threadIdx.x;
    if (i < n1) {
        int cid = (cell_coord(xyz1[3 * i + 2]) * GC +
                   cell_coord(xyz1[3 * i + 1])) * GC +
                   cell_coord(xyz1[3 * i + 0]);
        atomicAdd(&counts[cid], 1);
    }
    int nq = n2 * C;
    if (i < nq) {
        int n = i / C;
        float qx = xyz2[3 * n + 0] + motion[3 * i + 0];
        float qy = xyz2[3 * n + 1] + motion[3 * i + 1];
        float qz = xyz2[3 * n + 2] + motion[3 * i + 2];
        q4[i] = make_float4(qx, qy, qz, __int_as_float(i));
        int cid = (cell_coord(qz) * GC + cell_coord(qy)) * GC + cell_coord(qx);
        atomicAdd(&qcounts[cid], 1);
    }
}

__device__ void scan4096(const int* __restrict__ cnt, int* __restrict__ st,
                         int* __restrict__ cur, int* lds) {
    const int t = threadIdx.x;
    const int base = t * 16;
    int local[16];
    int s = 0;
    for (int k = 0; k < 16; ++k) { local[k] = cnt[base + k]; s += local[k]; }
    lds[t] = s;
    __syncthreads();
    for (int off = 1; off < 256; off <<= 1) {
        int v = (t >= off) ? lds[t - off] : 0;
        __syncthreads();
        lds[t] += v;
        __syncthreads();
    }
    int run = lds[t] - s;   // exclusive
    for (int k = 0; k < 16; ++k) {
        st[base + k] = run;
        cur[base + k] = run;
        run += local[k];
    }
    if (t == 255) st[NCELLS] = run;
}

__global__ __launch_bounds__(256) void scan2_kernel(
    const int* __restrict__ counts,  int* __restrict__ starts,  int* __restrict__ cursor,
    const int* __restrict__ qcounts, int* __restrict__ qstarts, int* __restrict__ qcursor) {
    __shared__ int lds[256];
    scan4096(counts, starts, cursor, lds);
    __syncthreads();
    scan4096(qcounts, qstarts, qcursor, lds);
}

// Fused: both scatters in one launch.
__global__ void fused_scatter_kernel(const float* __restrict__ xyz1, int n1,
                                     const float4* __restrict__ q4, int nq,
                                     int* __restrict__ cursor,
                                     int* __restrict__ qcursor,
                                     float4* __restrict__ sorted4,
                                     float4* __restrict__ qsorted4) {
    int i = blockIdx.x * blockDim.x + threadIdx.x;
    if (i < n1) {
        float x = xyz1[3 * i + 0];
        float y = xyz1[3 * i + 1];
        float z = xyz1[3 * i + 2];
        int cid = (cell_coord(z) * GC + cell_coord(y)) * GC + cell_coord(x);
        int pos = atomicAdd(&cursor[cid], 1);
        sorted4[pos] = make_float4(x, y, z, __int_as_float(i));
    }
    if (i < nq) {
        float4 Q = q4[i];
        int cid = (cell_coord(Q.z) * GC + cell_coord(Q.y)) * GC + cell_coord(Q.x);
        int pos = atomicAdd(&qcursor[cid], 1);
        qsorted4[pos] = Q;
    }
}

// (d, idx)-lexicographic insert: order-independent == validated stable scan.
__device__ __forceinline__ void top3_insert_lex(float d, int j,
                                                float& bd0, float& bd1, float& bd2,
                                                int& bi0, int& bi1, int& bi2) {
    if (d < bd2 || (d == bd2 && j < bi2)) {
        if (d < bd1 || (d == bd1 && j < bi1)) {
            bd2 = bd1; bi2 = bi1;
            if (d < bd0 || (d == bd0 && j < bi0)) {
                bd1 = bd0; bi1 = bi0;
                bd0 = d;   bi0 = j;
            } else {
                bd1 = d;   bi1 = j;
            }
        } else {
            bd2 = d;       bi2 = j;
        }
    }
}

// Validated candidate evaluation (round 8 roundings, rsq recomputed bit-equal)
__device__ __forceinline__ void eval_candidate(
    float4 r, float qx, float qy, float qz, float qsq,
    float& bd0, float& bd1, float& bd2, int& bi0, int& bi1, int& bi2) {
    int ridx = __float_as_int(r.w);
    float rsq = r.x * r.x + r.y * r.y;
    rsq = rsq + r.z * r.z;
    float t = fmaf(qz, r.z, fmaf(qy, r.y, qx * r.x));
    float h = qsq + rsq;
    float d = fmaxf(fmaf(-2.0f, t, h), 0.0f);
    top3_insert_lex(d, ridx, bd0, bd1, bd2, bi0, bi1, bi2);
}

// Rigorous certification radius after scanning cell-rings <= rho.
__device__ __forceinline__ float cert_radius(float qx, float qy, float qz,
                                             int icx, int icy, int icz, int rho) {
    float R = INFINITY;
    if (icx - rho > 0)      R = fminf(R, qx - (float)(icx - rho) * GH);
    if (icx + rho < GC - 1) R = fminf(R, (float)(icx + rho + 1) * GH - qx);
    if (icy - rho > 0)      R = fminf(R, qy - (float)(icy - rho) * GH);
    if (icy + rho < GC - 1) R = fminf(R, (float)(icy + rho + 1) * GH - qy);
    if (icz - rho > 0)      R = fminf(R, qz - (float)(icz - rho) * GH);
    if (icz + rho < GC - 1) R = fminf(R, (float)(icz + rho + 1) * GH - qz);
    return R;
}

// One block (2 waves) per cell. Stage 27-cell candidates into LDS once;
// waves SPLIT THE CANDIDATE LIST (wave0 [0,h), wave1 [h,total)) -> 8192
// waves (2x r12) and half-length serial chains. Wave1's per-query partial
// top-3 goes through LDS; wave0 merges (order-independent lex insert ->
// bit-exact), handles rare escalation, runs the validated epilogue.
__global__ __launch_bounds__(128, 8) void knn_cell_kernel(
    const float4* __restrict__ sorted4,
    const int*   __restrict__ starts,
    const float4* __restrict__ qsorted4,
    const int*   __restrict__ qstarts,
    const float* __restrict__ point1,
    float* __restrict__ out,
    int C)
{
#pragma clang fp contract(off)
    const int cell = blockIdx.x;
    const int qs = qstarts[cell];
    const int qe = qstarts[cell + 1];
    if (qs == qe) return;

    const int lane = threadIdx.x & 63;
    const int wave = threadIdx.x >> 6;

    const int icx = cell & (GC - 1);
    const int icy = (cell >> 4) & (GC - 1);
    const int icz = cell >> 8;

    __shared__ float4 cand[CAP];
    __shared__ int rowg0[9], rowlen[9], rowsta[9], rowlds[9];
    __shared__ int nrows_s, total_s, ovf_s;
    __shared__ float pbd[64][3];
    __shared__ int   pbi[64][3];

    if (threadIdx.x == 0) {
        const int x0 = max(icx - 1, 0);
        const int xw = min(icx + 1, GC - 1) - x0 + 1;
        int nr = 0, lds = 0, ovf = 0;
        for (int dz = -1; dz <= 1; ++dz) {
            int cz = icz + dz;
            if (cz < 0 || cz >= GC) continue;
            for (int dy = -1; dy <= 1; ++dy) {
                int cy = icy + dy;
                if (cy < 0 || cy >= GC) continue;
                int rb = (cz * GC + cy) * GC + x0;
                int g0 = starts[rb];
                int len = starts[rb + xw] - g0;
                int st = min(len, CAP - lds);
                if (st < 0) st = 0;
                rowg0[nr] = g0; rowlen[nr] = len;
                rowsta[nr] = st; rowlds[nr] = lds;
                lds += st;
                if (st < len) ovf = 1;
                ++nr;
            }
        }
        nrows_s = nr; total_s = lds; ovf_s = ovf;
    }
    __syncthreads();

    const int nrows = nrows_s;
    for (int r = 0; r < nrows; ++r) {
        const int st = rowsta[r], g0 = rowg0[r], lb = rowlds[r];
        for (int k = threadIdx.x; k < st; k += 128)
            cand[lb + k] = sorted4[g0 + k];
    }
    __syncthreads();

    const int total = total_s;
    const int ovf = ovf_s;
    const int half = total >> 1;
    const int k0 = wave ? half : 0;
    const int k1 = wave ? total : half;

    const int niter = (qe - qs + 63) >> 6;
    for (int it = 0; it < niter; ++it) {
        const int q = qs + it * 64 + lane;
        const bool active = q < qe;
        float4 Q = qsorted4[active ? q : qs];
        const float qx = Q.x, qy = Q.y, qz = Q.z;
        const int qid = __float_as_int(Q.w);
        float qsq = qx * qx + qy * qy;
        qsq = qsq + qz * qz;

        float bd0 = INFINITY, bd1 = INFINITY, bd2 = INFINITY;
        int   bi0 = 0,        bi1 = 0,        bi2 = 0;

        // 4x unrolled: batch 4 independent LDS reads before the insert chain
        int k = k0;
        for (; k + 4 <= k1; k += 4) {
            float4 c0 = cand[k + 0];
            float4 c1 = cand[k + 1];
            float4 c2 = cand[k + 2];
            float4 c3 = cand[k + 3];
            eval_candidate(c0, qx, qy, qz, qsq, bd0, bd1, bd2, bi0, bi1, bi2);
            eval_candidate(c1, qx, qy, qz, qsq, bd0, bd1, bd2, bi0, bi1, bi2);
            eval_candidate(c2, qx, qy, qz, qsq, bd0, bd1, bd2, bi0, bi1, bi2);
            eval_candidate(c3, qx, qy, qz, qsq, bd0, bd1, bd2, bi0, bi1, bi2);
        }
        for (; k < k1; ++k)
            eval_candidate(cand[k], qx, qy, qz, qsq, bd0, bd1, bd2, bi0, bi1, bi2);

        if (wave == 1) {
            pbd[lane][0] = bd0; pbd[lane][1] = bd1; pbd[lane][2] = bd2;
            pbi[lane][0] = bi0; pbi[lane][1] = bi1; pbi[lane][2] = bi2;
        }
        __syncthreads();

        if (wave == 0) {
            // merge wave1 partial (order-independent lex insert)
            for (int m = 0; m < 3; ++m) {
                float d = pbd[lane][m];
                if (d < INFINITY)
                    top3_insert_lex(d, pbi[lane][m], bd0, bd1, bd2, bi0, bi1, bi2);
            }
            if (ovf) {  // LDS overflow remainder (practically never taken)
                for (int r = 0; r < nrows; ++r)
                    for (int kk = rowsta[r]; kk < rowlen[r]; ++kk)
                        eval_candidate(sorted4[rowg0[r] + kk], qx, qy, qz, qsq,
                                       bd0, bd1, bd2, bi0, bi1, bi2);
            }
            // rigorous ring-1 certification; rare escalation to rings >= 2
            float R = cert_radius(qx, qy, qz, icx, icy, icz, 1);
            if (!(bd2 + MARGIN <= R * R)) {
                for (int rho = 2; rho < GC; ++rho) {
                    for (int dz = -rho; dz <= rho; ++dz) {
                        int cz = icz + dz;
                        if (cz < 0 || cz >= GC) continue;
                        int adz = (dz < 0) ? -dz : dz;
                        for (int dy = -rho; dy <= rho; ++dy) {
                            int cy = icy + dy;
                            if (cy < 0 || cy >= GC) continue;
                            int ady = (dy < 0) ? -dy : dy;
                            int step = (adz == rho || ady == rho) ? 1 : 2 * rho;
                            for (int dx = -rho; dx <= rho; dx += step) {
                                int cx = icx + dx;
                                if (cx < 0 || cx >= GC) continue;
                                int cid = (cz * GC + cy) * GC + cx;
                                int s = starts[cid];
                                int e = starts[cid + 1];
                                for (; s < e; ++s)
                                    eval_candidate(sorted4[s], qx, qy, qz, qsq,
                                                   bd0, bd1, bd2, bi0, bi1, bi2);
                            }
                        }
                    }
                    float Rr = cert_radius(qx, qy, qz, icx, icy, icz, rho);
                    if (bd2 + MARGIN <= Rr * Rr) break;  // Rr=INF also breaks
                }
            }

            if (active) {
                // epilogue, numpy fp32 order (validated round 8)
                float dd0 = bd0 + KNN_EPS;
                float dd1 = bd1 + KNN_EPS;
                float dd2 = bd2 + KNN_EPS;

                float w0 = 1.0f / dd0;
                float w1 = 1.0f / dd1;
                float w2 = 1.0f / dd2;
                float s  = w0 + w1;
                s = s + w2;
                float m = fmaxf(s, 3.0f);
                w0 = w0 / m;
                w1 = w1 / m;
                w2 = w2 / m;

                const int c = qid - (qid / C) * C;
                float p0 = point1[bi0 * C + c];
                float p1 = point1[bi1 * C + c];
                float p2 = point1[bi2 * C + c];

                float acc = w0 * p0 + w1 * p1;
                acc = acc + w2 * p2;
                out[qid] = acc;
            }
        }
        __syncthreads();  // protect pbd/pbi reuse next iteration
    }
}

extern "C" void kernel_launch(void* const* d_in, const int* in_sizes, int n_in,
                              void* d_out, int out_size, void* d_ws, size_t ws_size,
                              hipStream_t stream) {
    const float* xyz1   = (const float*)d_in[0];
    const float* point1 = (const float*)d_in[1];
    const float* xyz2   = (const float*)d_in[2];
    const float* motion = (const float*)d_in[3];
    float* out = (float*)d_out;

    const int n1 = in_sizes[0] / 3;
    const int n2 = in_sizes[2] / 3;
    const int C  = in_sizes[1] / n1;
    const int nq = n2 * C;

    // ws layout (~5.6 MB total)
    char* ws = (char*)d_ws;
    size_t off = 0;
    auto alloc = [&](size_t bytes) {
        char* p = ws + off;
        off = (off + bytes + 255) & ~(size_t)255;
        return p;
    };
    float4* sorted4  = (float4*)alloc((size_t)n1 * 16);
    float4* q4       = (float4*)alloc((size_t)nq * 16);
    float4* qsorted4 = (float4*)alloc((size_t)nq * 16);
    int* countsBoth  = (int*)alloc((size_t)2 * NCELLS * 4);  // counts | qcounts
    int* starts      = (int*)alloc((size_t)(NCELLS + 1) * 4);
    int* qstarts     = (int*)alloc((size_t)(NCELLS + 1) * 4);
    int* cursor      = (int*)alloc((size_t)NCELLS * 4);
    int* qcursor     = (int*)alloc((size_t)NCELLS * 4);
    int* counts  = countsBoth;
    int* qcounts = countsBoth + NCELLS;

    const int nmax = (n1 > nq) ? n1 : nq;

    hipMemsetAsync(countsBoth, 0, (size_t)2 * NCELLS * 4, stream);
    fused_count_kernel<<<(nmax + 255) / 256, 256, 0, stream>>>(
        xyz1, n1, xyz2, motion, q4, counts, qcounts, n2, C);
    scan2_kernel<<<1, 256, 0, stream>>>(counts, starts, cursor,
                                        qcounts, qstarts, qcursor);
    fused_scatter_kernel<<<(nmax + 255) / 256, 256, 0, stream>>>(
        xyz1, n1, q4, nq, cursor, qcursor, sorted4, qsorted4);
    knn_cell_kernel<<<NCELLS, 128, 0, stream>>>(
        sorted4, starts, qsorted4, qstarts, point1, out, C);
}